// Round 5
// baseline (398.169 us; speedup 1.0000x reference)
//
#include <hip/hip_runtime.h>
#include <hip/hip_bf16.h>
#include <cstdint>
#include <cstddef>

#define N_ROWS 8192
#define HDIM 512
#define INDIM 128
#define NHEADS 4
#define NNB 8

typedef __bf16 bf16_t;
typedef __bf16 bf16x8 __attribute__((ext_vector_type(8)));
typedef __bf16 bf16x4 __attribute__((ext_vector_type(4)));
typedef __bf16 bf16x2 __attribute__((ext_vector_type(2)));
typedef float f32x4 __attribute__((ext_vector_type(4)));

__device__ __forceinline__ float sigmoidf_(float x) { return 1.0f / (1.0f + expf(-x)); }

__device__ __forceinline__ void load_lds16(const void* g, void* l) {
  __builtin_amdgcn_global_load_lds(
      (const __attribute__((address_space(1))) void*)g,
      (__attribute__((address_space(3))) void*)l, 16, 0, 0);
}

// ---------------------------------------------------------------------------
// Pack: W1 = bf16([w_fg; w_ig]) (1024 x 2048),
//       W2i = bf16 gate-interleaved [w_ih | w_hh] (2048 x 640), row' = q*4+g,
//       b2[c'] = b_ih + b_hh (interleaved), A2[:, 0:128] = bf16(x)
// ---------------------------------------------------------------------------
__global__ __launch_bounds__(256) void pack_kernel(
    const float* __restrict__ w_fg, const float* __restrict__ w_ig,
    const float* __restrict__ w_ih, const float* __restrict__ w_hh,
    const float* __restrict__ b_ih, const float* __restrict__ b_hh,
    const float* __restrict__ x,
    bf16_t* __restrict__ W1, bf16_t* __restrict__ W2i,
    float* __restrict__ b2, bf16_t* __restrict__ A2)
{
  int idx = blockIdx.x * 256 + threadIdx.x;
  if (idx < 1024 * 2048) {
    int r = idx >> 11, k = idx & 2047;
    float v = (r < 512) ? w_fg[(size_t)r * 2048 + k] : w_ig[(size_t)(r - 512) * 2048 + k];
    W1[idx] = (bf16_t)v;
    return;
  }
  idx -= 1024 * 2048;
  if (idx < 2048 * 640) {
    int r = idx / 640, k = idx - r * 640;       // r = orig gate-major row g*512+q
    int rp = (r & 511) * 4 + (r >> 9);          // interleaved row q*4+g
    float v = (k < 128) ? w_ih[(size_t)r * 128 + k] : w_hh[(size_t)r * 512 + (k - 128)];
    W2i[(size_t)rp * 640 + k] = (bf16_t)v;
    return;
  }
  idx -= 2048 * 640;
  if (idx < 2048) {
    int q = idx >> 2, g = idx & 3;
    b2[idx] = b_ih[g * 512 + q] + b_hh[g * 512 + q];
    return;
  }
  idx -= 2048;
  if (idx < N_ROWS * INDIM) {
    int n = idx >> 7, cc = idx & 127;
    A2[(size_t)n * 640 + cc] = (bf16_t)x[idx];
  }
}

// ---------------------------------------------------------------------------
// Attention + aggregation: per-row softmax over 8 neighbors, agg -> bf16
// ---------------------------------------------------------------------------
__global__ __launch_bounds__(256) void attn_agg_kernel(
    const float* __restrict__ h, const float* __restrict__ hs,
    const float* __restrict__ a_src, bf16_t* __restrict__ agg)
{
  __shared__ float s_hs[NNB][HDIM];
  __shared__ float s_h[HDIM];
  __shared__ float s_logit[NNB][NHEADS];
  __shared__ float s_self[NHEADS];

  const int n = blockIdx.x;
  const int t = threadIdx.x;
  const float* hs_n = hs + (size_t)n * (NNB * HDIM);
  const float* h_n  = h  + (size_t)n * HDIM;

  {
    const float4* s4 = (const float4*)hs_n;
    float4* d4 = (float4*)&s_hs[0][0];
#pragma unroll
    for (int i = 0; i < 4; ++i) d4[t + i * 256] = s4[t + i * 256];
    if (t < HDIM / 4) ((float4*)s_h)[t] = ((const float4*)h_n)[t];
  }
  __syncthreads();

  const int wave = t >> 6, lane = t & 63;
#pragma unroll
  for (int kk = 0; kk < 2; ++kk) {
    const int k = wave * 2 + kk;
    float acc0 = 0.f, acc1 = 0.f, acc2 = 0.f, acc3 = 0.f;
#pragma unroll
    for (int i = 0; i < HDIM / 64; ++i) {
      const int hh = i * 64 + lane;
      const float v = s_hs[k][hh];
      const float4 av = *(const float4*)(a_src + (size_t)(HDIM + hh) * NHEADS);
      acc0 += v * av.x; acc1 += v * av.y; acc2 += v * av.z; acc3 += v * av.w;
    }
    float accs[NHEADS] = {acc0, acc1, acc2, acc3};
#pragma unroll
    for (int m = 0; m < NHEADS; ++m) {
      float a = accs[m];
#pragma unroll
      for (int off = 32; off > 0; off >>= 1) a += __shfl_xor(a, off);
      if (lane == 0) s_logit[k][m] = a;
    }
  }
  if (wave == 0) {
    float acc0 = 0.f, acc1 = 0.f, acc2 = 0.f, acc3 = 0.f;
#pragma unroll
    for (int i = 0; i < HDIM / 64; ++i) {
      const int hh = i * 64 + lane;
      const float v = s_h[hh];
      const float4 av = *(const float4*)(a_src + (size_t)hh * NHEADS);
      acc0 += v * av.x; acc1 += v * av.y; acc2 += v * av.z; acc3 += v * av.w;
    }
    float accs[NHEADS] = {acc0, acc1, acc2, acc3};
#pragma unroll
    for (int m = 0; m < NHEADS; ++m) {
      float a = accs[m];
#pragma unroll
      for (int off = 32; off > 0; off >>= 1) a += __shfl_xor(a, off);
      if (lane == 0) s_self[m] = a;
    }
  }
  __syncthreads();

  float w[NNB][NHEADS];
#pragma unroll
  for (int m = 0; m < NHEADS; ++m) {
    const float sm = s_self[m];
    float mx = -1e30f;
#pragma unroll
    for (int k = 0; k < NNB; ++k) {
      float l = sm + s_logit[k][m];
      l = (l >= 0.f) ? l : 0.2f * l;
      w[k][m] = l;
      mx = fmaxf(mx, l);
    }
    float sum = 0.f;
#pragma unroll
    for (int k = 0; k < NNB; ++k) { const float e = expf(w[k][m] - mx); w[k][m] = e; sum += e; }
    const float inv = 1.f / sum;
#pragma unroll
    for (int k = 0; k < NNB; ++k) w[k][m] *= inv;
  }

  bf16_t* agg_n = agg + (size_t)n * (NHEADS * HDIM);
  const int hh = t * 2;
  float e0[NNB], e1[NNB];
#pragma unroll
  for (int k = 0; k < NNB; ++k) { e0[k] = s_hs[k][hh]; e1[k] = s_hs[k][hh + 1]; }
#pragma unroll
  for (int m = 0; m < NHEADS; ++m) {
    float a0 = 0.f, a1 = 0.f;
#pragma unroll
    for (int k = 0; k < NNB; ++k) { a0 += w[k][m] * e0[k]; a1 += w[k][m] * e1[k]; }
    bf16x2 pk; pk[0] = (bf16_t)a0; pk[1] = (bf16_t)a1;
    *(bf16x2*)(agg_n + m * HDIM + hh) = pk;
  }
}

// ---------------------------------------------------------------------------
// 2-phase double-buffered bf16 GEMM, 128x128 tile, BK=64, 4 waves (64x64 each).
// Counted vmcnt(8): next tile's 8 global_load_lds stay in flight across the
// barrier (T4). Raw s_barrier + sched_barrier fences (no implicit vmcnt(0)
// drain that __syncthreads would emit).
// EPI 1: spatial-gate epilogue (cprime fp32, h' -> A2 bf16).
// EPI 2: gate-interleaved cols; fused LSTM finish via LDS -> writes out.
// ---------------------------------------------------------------------------
template <int EPI>
__global__ __launch_bounds__(256, 2) void gemm2p_kernel(
    const bf16_t* __restrict__ A, int lda,
    const bf16_t* __restrict__ Bt, int ldb, int K,
    const float* __restrict__ p0, const float* __restrict__ p1,
    const float* __restrict__ p2, const float* __restrict__ p3,
    float* __restrict__ q0, bf16_t* __restrict__ q1,
    float* __restrict__ out)
{
  __shared__ union {
    struct { bf16_t A[2][128][64]; bf16_t B[2][128][64]; } st;  // 64 KB
    float epi[128][128];                                        // 64 KB
  } sm;

  const int tid  = threadIdx.x;
  const int wave = tid >> 6, lane = tid & 63;
  const int wr = wave >> 1, wc = wave & 1;
  const int bm0 = blockIdx.x * 128;
  const int bn0 = blockIdx.y * 128;

  f32x4 acc[4][4] = {};

  // staging: thread covers rows (tid>>3)+32r, 16B chunk (tid&7); LDS dest is
  // wave-linear (offset == tid*16 within each 32-row round) as global_load_lds requires.
  const int srow = tid >> 3;
  const int sch8 = (tid & 7) * 8;
  const bf16_t* Ag = A  + (size_t)(bm0 + srow) * lda + sch8;
  const bf16_t* Bg = Bt + (size_t)(bn0 + srow) * ldb + sch8;

  const int frow = lane & 15;
  const int fk   = (lane >> 4) * 8;

  auto FB = [&]() {
    __builtin_amdgcn_sched_barrier(0);
    __builtin_amdgcn_s_barrier();
    __builtin_amdgcn_sched_barrier(0);
  };
  auto STAGE = [&](int buf, int k0) {
#pragma unroll
    for (int r = 0; r < 4; ++r)
      load_lds16(Ag + (size_t)r * 32 * lda + k0, &sm.st.A[buf][srow + 32 * r][sch8]);
#pragma unroll
    for (int r = 0; r < 4; ++r)
      load_lds16(Bg + (size_t)r * 32 * ldb + k0, &sm.st.B[buf][srow + 32 * r][sch8]);
  };
  auto COMPUTE = [&](int buf) {
#pragma unroll
    for (int kk = 0; kk < 2; ++kk) {
      bf16x8 af[4], bv[4];
#pragma unroll
      for (int i = 0; i < 4; ++i)
        af[i] = *(const bf16x8*)&sm.st.A[buf][wr * 64 + i * 16 + frow][kk * 32 + fk];
#pragma unroll
      for (int j = 0; j < 4; ++j)
        bv[j] = *(const bf16x8*)&sm.st.B[buf][wc * 64 + j * 16 + frow][kk * 32 + fk];
#pragma unroll
      for (int i = 0; i < 4; ++i)
#pragma unroll
        for (int j = 0; j < 4; ++j)
          acc[i][j] = __builtin_amdgcn_mfma_f32_16x16x32_bf16(af[i], bv[j], acc[i][j], 0, 0, 0);
    }
  };

  const int nt = K >> 6;  // BK = 64
  STAGE(0, 0);
  for (int t = 0; t < nt - 1; ++t) {
    STAGE((t + 1) & 1, (t + 1) * 64);
    asm volatile("s_waitcnt vmcnt(8)" ::: "memory");  // tile t landed; t+1 in flight
    FB();
    COMPUTE(t & 1);
    FB();
  }
  asm volatile("s_waitcnt vmcnt(0)" ::: "memory");
  FB();
  COMPUTE((nt - 1) & 1);

  const int col_in = lane & 15;
  const int row_in = (lane >> 4) * 4;

  if (EPI == 1) {
#pragma unroll
    for (int i = 0; i < 4; ++i) {
#pragma unroll
      for (int j = 0; j < 4; ++j) {
        const int col = bn0 + wc * 64 + j * 16 + col_in;
#pragma unroll
        for (int r = 0; r < 4; ++r) {
          const int row = bm0 + wr * 64 + i * 16 + row_in + r;
          const float v = acc[i][j][r];
          if (col < 512) {
            const float s = sigmoidf_(v + p0[col]);
            q0[(size_t)row * 512 + col] = p2[(size_t)row * 512 + col] * s;
          } else {
            const int jj = col - 512;
            const float s = sigmoidf_(v + p1[jj]);
            q1[(size_t)row * 640 + 128 + jj] = (bf16_t)(p3[(size_t)row * 512 + jj] * s);
          }
        }
      }
    }
  } else {
    // fused LSTM finish. cols are gate-interleaved: local col c = qi*4+g.
    FB();  // all K-loop LDS reads done in every wave before overwriting union
#pragma unroll
    for (int i = 0; i < 4; ++i)
#pragma unroll
      for (int j = 0; j < 4; ++j)
#pragma unroll
        for (int r = 0; r < 4; ++r)
          sm.epi[wr * 64 + i * 16 + row_in + r][wc * 64 + j * 16 + col_in] = acc[i][j][r];
    asm volatile("s_waitcnt lgkmcnt(0)" ::: "memory");  // ds_writes visible
    FB();
    const int q0i = bn0 >> 2;  // first global q of this block
#pragma unroll
    for (int pass = 0; pass < 16; ++pass) {
      const int idx = pass * 256 + tid;
      const int r  = idx >> 5;       // 0..127 local row
      const int qi = idx & 31;       // 0..31 local q
      const float4 g4 = *(const float4*)&sm.epi[r][qi * 4];
      const float4 bb = *(const float4*)&p0[(size_t)(q0i + qi) * 4];  // b2
      const int grow = bm0 + r;
      const int q    = q0i + qi;
      const float cp = p1[(size_t)grow * 512 + q];  // cprime
      const float ig = sigmoidf_(g4.x + bb.x);
      const float fg = sigmoidf_(g4.y + bb.y);
      const float gg = tanhf(g4.z + bb.z);
      const float og = sigmoidf_(g4.w + bb.w);
      const float cn = fg * cp + ig * gg;
      const float hn = og * tanhf(cn);
      out[(size_t)grow * 512 + q] = hn;
      out[(size_t)N_ROWS * 512 + (size_t)grow * 512 + q] = cn;
    }
  }
}

// ---------------------------------------------------------------------------
extern "C" void kernel_launch(void* const* d_in, const int* in_sizes, int n_in,
                              void* d_out, int out_size, void* d_ws, size_t ws_size,
                              hipStream_t stream) {
  const float* x     = (const float*)d_in[0];
  const float* h     = (const float*)d_in[1];
  const float* c     = (const float*)d_in[2];
  const float* hsp   = (const float*)d_in[3];
  const float* a_src = (const float*)d_in[4];
  const float* w_fg  = (const float*)d_in[5];
  const float* b_fg  = (const float*)d_in[6];
  const float* w_ig  = (const float*)d_in[7];
  const float* b_ig  = (const float*)d_in[8];
  const float* w_ih  = (const float*)d_in[9];
  const float* w_hh  = (const float*)d_in[10];
  const float* b_ih  = (const float*)d_in[11];
  const float* b_hh  = (const float*)d_in[12];
  float* out = (float*)d_out;

  uint8_t* ws = (uint8_t*)d_ws;
  bf16_t* agg    = (bf16_t*)(ws);                 // 8192*2048*2 = 33,554,432
  bf16_t* W1     = (bf16_t*)(ws + 33554432);      // 1024*2048*2 =  4,194,304
  bf16_t* W2i    = (bf16_t*)(ws + 37748736);      // 2048*640*2  =  2,621,440
  float*  b2     = (float*) (ws + 40370176);      // 2048*4      =      8,192
  bf16_t* A2     = (bf16_t*)(ws + 40378368);      // 8192*640*2  = 10,485,760
  float*  cprime = (float*) (ws + 50864128);      // 8192*512*4  = 16,777,216
  // total 67,641,344 bytes

  pack_kernel<<<17416, 256, 0, stream>>>(w_fg, w_ig, w_ih, w_hh, b_ih, b_hh, x,
                                         W1, W2i, b2, A2);
  attn_agg_kernel<<<N_ROWS, 256, 0, stream>>>(h, hsp, a_src, agg);
  gemm2p_kernel<1><<<dim3(64, 8), 256, 0, stream>>>(
      agg, 2048, W1, 2048, 2048, b_fg, b_ig, c, h, cprime, A2, nullptr);
  gemm2p_kernel<2><<<dim3(64, 16), 256, 0, stream>>>(
      A2, 640, W2i, 640, 640, b2, cprime, nullptr, nullptr, nullptr, nullptr, out);
}

// Round 6
// 217.166 us; speedup vs baseline: 1.8335x; 1.8335x over previous
//
#include <hip/hip_runtime.h>
#include <hip/hip_bf16.h>
#include <cstdint>
#include <cstddef>

#define N_ROWS 8192
#define HDIM 512
#define INDIM 128
#define NHEADS 4
#define NNB 8

typedef __bf16 bf16_t;
typedef __bf16 bf16x8 __attribute__((ext_vector_type(8)));
typedef __bf16 bf16x4 __attribute__((ext_vector_type(4)));
typedef __bf16 bf16x2 __attribute__((ext_vector_type(2)));
typedef float f32x4 __attribute__((ext_vector_type(4)));

__device__ __forceinline__ float sigmoidf_(float x) { return 1.0f / (1.0f + expf(-x)); }

__device__ __forceinline__ void load_lds16(const void* g, void* l) {
  __builtin_amdgcn_global_load_lds(
      (const __attribute__((address_space(1))) void*)g,
      (__attribute__((address_space(3))) void*)l, 16, 0, 0);
}

// ---------------------------------------------------------------------------
// Pack: W1 = bf16([w_fg; w_ig]) (1024 x 2048),
//       W2i = bf16 gate-interleaved [w_ih | w_hh] (2048 x 640), row' = q*4+g,
//       b2[c'] = b_ih + b_hh (interleaved), A2[:, 0:128] = bf16(x)
// ---------------------------------------------------------------------------
__global__ __launch_bounds__(256) void pack_kernel(
    const float* __restrict__ w_fg, const float* __restrict__ w_ig,
    const float* __restrict__ w_ih, const float* __restrict__ w_hh,
    const float* __restrict__ b_ih, const float* __restrict__ b_hh,
    const float* __restrict__ x,
    bf16_t* __restrict__ W1, bf16_t* __restrict__ W2i,
    float* __restrict__ b2, bf16_t* __restrict__ A2)
{
  int idx = blockIdx.x * 256 + threadIdx.x;
  if (idx < 1024 * 2048) {
    int r = idx >> 11, k = idx & 2047;
    float v = (r < 512) ? w_fg[(size_t)r * 2048 + k] : w_ig[(size_t)(r - 512) * 2048 + k];
    W1[idx] = (bf16_t)v;
    return;
  }
  idx -= 1024 * 2048;
  if (idx < 2048 * 640) {
    int r = idx / 640, k = idx - r * 640;       // r = orig gate-major row g*512+q
    int rp = (r & 511) * 4 + (r >> 9);          // interleaved row q*4+g
    float v = (k < 128) ? w_ih[(size_t)r * 128 + k] : w_hh[(size_t)r * 512 + (k - 128)];
    W2i[(size_t)rp * 640 + k] = (bf16_t)v;
    return;
  }
  idx -= 2048 * 640;
  if (idx < 2048) {
    int q = idx >> 2, g = idx & 3;
    b2[idx] = b_ih[g * 512 + q] + b_hh[g * 512 + q];
    return;
  }
  idx -= 2048;
  if (idx < N_ROWS * INDIM) {
    int n = idx >> 7, cc = idx & 127;
    A2[(size_t)n * 640 + cc] = (bf16_t)x[idx];
  }
}

// ---------------------------------------------------------------------------
// Attention + aggregation: per-row softmax over 8 neighbors, agg -> bf16
// ---------------------------------------------------------------------------
__global__ __launch_bounds__(256) void attn_agg_kernel(
    const float* __restrict__ h, const float* __restrict__ hs,
    const float* __restrict__ a_src, bf16_t* __restrict__ agg)
{
  __shared__ float s_hs[NNB][HDIM];
  __shared__ float s_h[HDIM];
  __shared__ float s_logit[NNB][NHEADS];
  __shared__ float s_self[NHEADS];

  const int n = blockIdx.x;
  const int t = threadIdx.x;
  const float* hs_n = hs + (size_t)n * (NNB * HDIM);
  const float* h_n  = h  + (size_t)n * HDIM;

  {
    const float4* s4 = (const float4*)hs_n;
    float4* d4 = (float4*)&s_hs[0][0];
#pragma unroll
    for (int i = 0; i < 4; ++i) d4[t + i * 256] = s4[t + i * 256];
    if (t < HDIM / 4) ((float4*)s_h)[t] = ((const float4*)h_n)[t];
  }
  __syncthreads();

  const int wave = t >> 6, lane = t & 63;
#pragma unroll
  for (int kk = 0; kk < 2; ++kk) {
    const int k = wave * 2 + kk;
    float acc0 = 0.f, acc1 = 0.f, acc2 = 0.f, acc3 = 0.f;
#pragma unroll
    for (int i = 0; i < HDIM / 64; ++i) {
      const int hh = i * 64 + lane;
      const float v = s_hs[k][hh];
      const float4 av = *(const float4*)(a_src + (size_t)(HDIM + hh) * NHEADS);
      acc0 += v * av.x; acc1 += v * av.y; acc2 += v * av.z; acc3 += v * av.w;
    }
    float accs[NHEADS] = {acc0, acc1, acc2, acc3};
#pragma unroll
    for (int m = 0; m < NHEADS; ++m) {
      float a = accs[m];
#pragma unroll
      for (int off = 32; off > 0; off >>= 1) a += __shfl_xor(a, off);
      if (lane == 0) s_logit[k][m] = a;
    }
  }
  if (wave == 0) {
    float acc0 = 0.f, acc1 = 0.f, acc2 = 0.f, acc3 = 0.f;
#pragma unroll
    for (int i = 0; i < HDIM / 64; ++i) {
      const int hh = i * 64 + lane;
      const float v = s_h[hh];
      const float4 av = *(const float4*)(a_src + (size_t)hh * NHEADS);
      acc0 += v * av.x; acc1 += v * av.y; acc2 += v * av.z; acc3 += v * av.w;
    }
    float accs[NHEADS] = {acc0, acc1, acc2, acc3};
#pragma unroll
    for (int m = 0; m < NHEADS; ++m) {
      float a = accs[m];
#pragma unroll
      for (int off = 32; off > 0; off >>= 1) a += __shfl_xor(a, off);
      if (lane == 0) s_self[m] = a;
    }
  }
  __syncthreads();

  float w[NNB][NHEADS];
#pragma unroll
  for (int m = 0; m < NHEADS; ++m) {
    const float sm = s_self[m];
    float mx = -1e30f;
#pragma unroll
    for (int k = 0; k < NNB; ++k) {
      float l = sm + s_logit[k][m];
      l = (l >= 0.f) ? l : 0.2f * l;
      w[k][m] = l;
      mx = fmaxf(mx, l);
    }
    float sum = 0.f;
#pragma unroll
    for (int k = 0; k < NNB; ++k) { const float e = expf(w[k][m] - mx); w[k][m] = e; sum += e; }
    const float inv = 1.f / sum;
#pragma unroll
    for (int k = 0; k < NNB; ++k) w[k][m] *= inv;
  }

  bf16_t* agg_n = agg + (size_t)n * (NHEADS * HDIM);
  const int hh = t * 2;
  float e0[NNB], e1[NNB];
#pragma unroll
  for (int k = 0; k < NNB; ++k) { e0[k] = s_hs[k][hh]; e1[k] = s_hs[k][hh + 1]; }
#pragma unroll
  for (int m = 0; m < NHEADS; ++m) {
    float a0 = 0.f, a1 = 0.f;
#pragma unroll
    for (int k = 0; k < NNB; ++k) { a0 += w[k][m] * e0[k]; a1 += w[k][m] * e1[k]; }
    bf16x2 pk; pk[0] = (bf16_t)a0; pk[1] = (bf16_t)a1;
    *(bf16x2*)(agg_n + m * HDIM + hh) = pk;
  }
}

// ---------------------------------------------------------------------------
// 2-phase double-buffered bf16 GEMM, 128x128 tile, BK=64, 4 waves (64x64 each).
// Counted vmcnt(8) keeps next tile's loads in flight across the barrier (T4).
// LDS XOR-swizzle (T2, rule-#21 compliant): global SOURCE pre-swizzled
// (chunk ^= row&7), LDS dest linear (global_load_lds requirement), ds_read
// address swizzled with the same involution -> 2-way (free) bank access
// instead of 16-way on the 128B-stride rows.
// EPI 1: spatial-gate epilogue (cprime fp32, h' -> A2 bf16).
// EPI 2: gate-interleaved cols; fused LSTM finish via LDS -> writes out.
// ---------------------------------------------------------------------------
template <int EPI>
__global__ __launch_bounds__(256, 2) void gemm2p_kernel(
    const bf16_t* __restrict__ A, int lda,
    const bf16_t* __restrict__ Bt, int ldb, int K,
    const float* __restrict__ p0, const float* __restrict__ p1,
    const float* __restrict__ p2, const float* __restrict__ p3,
    float* __restrict__ q0, bf16_t* __restrict__ q1,
    float* __restrict__ out)
{
  __shared__ union {
    struct { bf16_t A[2][128][64]; bf16_t B[2][128][64]; } st;  // 64 KB
    float epi[128][128];                                        // 64 KB
  } sm;

  const int tid  = threadIdx.x;
  const int wave = tid >> 6, lane = tid & 63;
  const int wr = wave >> 1, wc = wave & 1;
  const int bm0 = blockIdx.x * 128;
  const int bn0 = blockIdx.y * 128;

  f32x4 acc[4][4] = {};

  // staging: thread covers physical (row = srow+32r, 16B chunk sch); the
  // GLOBAL source chunk is pre-swizzled: gch = sch ^ (row&7) = sch ^ (srow&7)
  // (32r doesn't change row&7). LDS dest stays wave-linear (tid*16 + r*4096).
  const int srow = tid >> 3;            // 0..31
  const int sch  = tid & 7;             // 16B chunk
  const int gch8 = (sch ^ (srow & 7)) * 8;  // pre-swizzled global bf16 offset
  const bf16_t* Ag = A  + (size_t)(bm0 + srow) * lda + gch8;
  const bf16_t* Bg = Bt + (size_t)(bn0 + srow) * ldb + gch8;

  const int frow = lane & 15;
  const int q16  = (lane >> 4) * 16;    // byte offset of lane-quarter
  const int sx   = (frow & 7) * 16;     // read-side swizzle XOR (bytes)

  auto FB = [&]() {
    __builtin_amdgcn_sched_barrier(0);
    __builtin_amdgcn_s_barrier();
    __builtin_amdgcn_sched_barrier(0);
  };
  auto STAGE = [&](int buf, int k0) {
#pragma unroll
    for (int r = 0; r < 4; ++r)
      load_lds16(Ag + (size_t)r * 32 * lda + k0, &sm.st.A[buf][srow + 32 * r][sch * 8]);
#pragma unroll
    for (int r = 0; r < 4; ++r)
      load_lds16(Bg + (size_t)r * 32 * ldb + k0, &sm.st.B[buf][srow + 32 * r][sch * 8]);
  };
  auto COMPUTE = [&](int buf) {
#pragma unroll
    for (int kk = 0; kk < 2; ++kk) {
      const int off = (kk * 64 + q16) ^ sx;  // swizzled byte offset within row
      bf16x8 af[4], bv[4];
#pragma unroll
      for (int i = 0; i < 4; ++i)
        af[i] = *(const bf16x8*)((const char*)&sm.st.A[buf][wr * 64 + i * 16 + frow][0] + off);
#pragma unroll
      for (int j = 0; j < 4; ++j)
        bv[j] = *(const bf16x8*)((const char*)&sm.st.B[buf][wc * 64 + j * 16 + frow][0] + off);
#pragma unroll
      for (int i = 0; i < 4; ++i)
#pragma unroll
        for (int j = 0; j < 4; ++j)
          acc[i][j] = __builtin_amdgcn_mfma_f32_16x16x32_bf16(af[i], bv[j], acc[i][j], 0, 0, 0);
    }
  };

  const int nt = K >> 6;  // BK = 64
  STAGE(0, 0);
  for (int t = 0; t < nt - 1; ++t) {
    STAGE((t + 1) & 1, (t + 1) * 64);
    asm volatile("s_waitcnt vmcnt(8)" ::: "memory");  // tile t landed; t+1 in flight
    FB();
    COMPUTE(t & 1);
    FB();
  }
  asm volatile("s_waitcnt vmcnt(0)" ::: "memory");
  FB();
  COMPUTE((nt - 1) & 1);

  const int col_in = lane & 15;
  const int row_in = (lane >> 4) * 4;

  if (EPI == 1) {
#pragma unroll
    for (int i = 0; i < 4; ++i) {
#pragma unroll
      for (int j = 0; j < 4; ++j) {
        const int col = bn0 + wc * 64 + j * 16 + col_in;
#pragma unroll
        for (int r = 0; r < 4; ++r) {
          const int row = bm0 + wr * 64 + i * 16 + row_in + r;
          const float v = acc[i][j][r];
          if (col < 512) {
            const float s = sigmoidf_(v + p0[col]);
            q0[(size_t)row * 512 + col] = p2[(size_t)row * 512 + col] * s;
          } else {
            const int jj = col - 512;
            const float s = sigmoidf_(v + p1[jj]);
            q1[(size_t)row * 640 + 128 + jj] = (bf16_t)(p3[(size_t)row * 512 + jj] * s);
          }
        }
      }
    }
  } else {
    // fused LSTM finish. cols are gate-interleaved: local col c = qi*4+g.
    FB();  // all K-loop LDS reads done in every wave before overwriting union
#pragma unroll
    for (int i = 0; i < 4; ++i)
#pragma unroll
      for (int j = 0; j < 4; ++j)
#pragma unroll
        for (int r = 0; r < 4; ++r)
          sm.epi[wr * 64 + i * 16 + row_in + r][wc * 64 + j * 16 + col_in] = acc[i][j][r];
    asm volatile("s_waitcnt lgkmcnt(0)" ::: "memory");  // ds_writes visible
    FB();
    const int q0i = bn0 >> 2;  // first global q of this block
#pragma unroll
    for (int pass = 0; pass < 16; ++pass) {
      const int idx = pass * 256 + tid;
      const int r  = idx >> 5;       // 0..127 local row
      const int qi = idx & 31;       // 0..31 local q
      const float4 g4 = *(const float4*)&sm.epi[r][qi * 4];
      const float4 bb = *(const float4*)&p0[(size_t)(q0i + qi) * 4];  // b2
      const int grow = bm0 + r;
      const int q    = q0i + qi;
      const float cp = p1[(size_t)grow * 512 + q];  // cprime
      const float ig = sigmoidf_(g4.x + bb.x);
      const float fg = sigmoidf_(g4.y + bb.y);
      const float gg = tanhf(g4.z + bb.z);
      const float og = sigmoidf_(g4.w + bb.w);
      const float cn = fg * cp + ig * gg;
      const float hn = og * tanhf(cn);
      out[(size_t)grow * 512 + q] = hn;
      out[(size_t)N_ROWS * 512 + (size_t)grow * 512 + q] = cn;
    }
  }
}

// ---------------------------------------------------------------------------
extern "C" void kernel_launch(void* const* d_in, const int* in_sizes, int n_in,
                              void* d_out, int out_size, void* d_ws, size_t ws_size,
                              hipStream_t stream) {
  const float* x     = (const float*)d_in[0];
  const float* h     = (const float*)d_in[1];
  const float* c     = (const float*)d_in[2];
  const float* hsp   = (const float*)d_in[3];
  const float* a_src = (const float*)d_in[4];
  const float* w_fg  = (const float*)d_in[5];
  const float* b_fg  = (const float*)d_in[6];
  const float* w_ig  = (const float*)d_in[7];
  const float* b_ig  = (const float*)d_in[8];
  const float* w_ih  = (const float*)d_in[9];
  const float* w_hh  = (const float*)d_in[10];
  const float* b_ih  = (const float*)d_in[11];
  const float* b_hh  = (const float*)d_in[12];
  float* out = (float*)d_out;

  uint8_t* ws = (uint8_t*)d_ws;
  bf16_t* agg    = (bf16_t*)(ws);                 // 8192*2048*2 = 33,554,432
  bf16_t* W1     = (bf16_t*)(ws + 33554432);      // 1024*2048*2 =  4,194,304
  bf16_t* W2i    = (bf16_t*)(ws + 37748736);      // 2048*640*2  =  2,621,440
  float*  b2     = (float*) (ws + 40370176);      // 2048*4      =      8,192
  bf16_t* A2     = (bf16_t*)(ws + 40378368);      // 8192*640*2  = 10,485,760
  float*  cprime = (float*) (ws + 50864128);      // 8192*512*4  = 16,777,216
  // total 67,641,344 bytes

  pack_kernel<<<17416, 256, 0, stream>>>(w_fg, w_ig, w_ih, w_hh, b_ih, b_hh, x,
                                         W1, W2i, b2, A2);
  attn_agg_kernel<<<N_ROWS, 256, 0, stream>>>(h, hsp, a_src, agg);
  gemm2p_kernel<1><<<dim3(64, 8), 256, 0, stream>>>(
      agg, 2048, W1, 2048, 2048, b_fg, b_ig, c, h, cprime, A2, nullptr);
  gemm2p_kernel<2><<<dim3(64, 16), 256, 0, stream>>>(
      A2, 640, W2i, 640, 640, b2, cprime, nullptr, nullptr, nullptr, nullptr, out);
}